// Round 2
// baseline (906.292 us; speedup 1.0000x reference)
//
#include <hip/hip_runtime.h>
#include <hip/hip_bf16.h>

typedef __hip_bfloat16 bf16;

#define HEADS 4
#define CDIM 64
#define HC 256
#define NEG 0.2f
#define BN_EPS 1e-5f

__device__ __forceinline__ float u2f(unsigned short u) { return __uint_as_float(((unsigned)u) << 16); }
__device__ __forceinline__ float leaky(float x) { return x > 0.f ? x : NEG * x; }

// order-preserving float<->uint encoding for atomicMax on signed floats
__device__ __forceinline__ unsigned enc(float f) {
    unsigned u = __float_as_uint(f);
    return (u & 0x80000000u) ? ~u : (u | 0x80000000u);
}
__device__ __forceinline__ float dec(unsigned k) {
    return (k & 0x80000000u) ? __uint_as_float(k ^ 0x80000000u) : __uint_as_float(~k);
}

// storage helpers (xl/xr may be f32 or bf16 depending on ws budget)
__device__ __forceinline__ void st1(float* p, float v) { *p = v; }
__device__ __forceinline__ void st1(bf16* p, float v) { *p = __float2bfloat16(v); }
__device__ __forceinline__ float ld1(const float* p) { return *p; }
__device__ __forceinline__ float ld1(const bf16* p) { return __bfloat162float(*p); }
__device__ __forceinline__ float4 ld4(const float* p) { return *reinterpret_cast<const float4*>(p); }
__device__ __forceinline__ float4 ld4(const bf16* p) {
    ushort4 u = *reinterpret_cast<const ushort4*>(p);
    return make_float4(u2f(u.x), u2f(u.y), u2f(u.z), u2f(u.w));
}

// ---------- xl = X@Wl, xr = X@Wr ----------
template <typename TS>
__global__ void gemm_xlxr(const float* __restrict__ X, int ldx, int K,
                          const float* __restrict__ Wl, const float* __restrict__ Wr,
                          TS* __restrict__ xl, TS* __restrict__ xr) {
    __shared__ float xrow[72];
    const int n = blockIdx.x;
    const int t = threadIdx.x;
    if (t < K) xrow[t] = X[(size_t)n * ldx + t];
    __syncthreads();
    float aL = 0.f, aR = 0.f;
    for (int k = 0; k < K; ++k) {
        const float xv = xrow[k];
        aL += xv * Wl[(size_t)k * HC + t];
        aR += xv * Wr[(size_t)k * HC + t];
    }
    st1(&xl[(size_t)n * HC + t], aL);
    st1(&xr[(size_t)n * HC + t], aR);
}

// ---------- edge scores + segment max (one wave per edge) ----------
template <typename TS>
__global__ void score_kernel(const TS* __restrict__ xl, const TS* __restrict__ xr,
                             const int* __restrict__ src, const int* __restrict__ dst,
                             const float* __restrict__ att,
                             float* __restrict__ score, unsigned* __restrict__ m,
                             int E, int EE) {
    const int tid = threadIdx.x;
    const int w = tid >> 6, lane = tid & 63;
    const int e = blockIdx.x * 4 + w;
    if (e >= EE) return;
    const int is = (e < E) ? src[e] : (e - E);
    const int id = (e < E) ? dst[e] : (e - E);

    const float4 a = ld4(xl + (size_t)is * HC + lane * 4);
    const float4 b = ld4(xr + (size_t)id * HC + lane * 4);
    const float4 av = *reinterpret_cast<const float4*>(att + lane * 4);

    float p = 0.f;
    p += av.x * leaky(a.x + b.x);
    p += av.y * leaky(a.y + b.y);
    p += av.z * leaky(a.z + b.z);
    p += av.w * leaky(a.w + b.w);

    // reduce within each 16-lane group (one head per group)
    #pragma unroll
    for (int o = 8; o; o >>= 1) p += __shfl_xor(p, o);

    if ((lane & 15) == 0) {
        const int h = lane >> 4;
        score[(size_t)e * 4 + h] = p;
        atomicMax(&m[(size_t)id * 4 + h], enc(p));
    }
}

// ---------- exp(score - max) + denominator ----------
__global__ void expv_kernel(float* __restrict__ score, const unsigned* __restrict__ m,
                            float* __restrict__ denom, const int* __restrict__ dst,
                            int E, int EE) {
    const long gid = (long)blockIdx.x * 256 + threadIdx.x;
    if (gid >= (long)EE * 4) return;
    const int e = (int)(gid >> 2), h = (int)(gid & 3);
    const int id = (e < E) ? dst[e] : (e - E);
    const float s = score[gid];
    const float mm = dec(m[(size_t)id * 4 + h]);
    const float ev = __expf(s - mm);
    score[gid] = ev;
    atomicAdd(&denom[(size_t)id * 4 + h], ev);
}

// ---------- aggregation: hagg[dst,c] += (1/4) sum_h alpha_eh * xl[src, h*64+c] ----------
template <typename TS>
__global__ void agg_kernel(const TS* __restrict__ xl, const float* __restrict__ score,
                           const float* __restrict__ denom,
                           const int* __restrict__ src, const int* __restrict__ dst,
                           float* __restrict__ hagg, int E, int EE) {
    const int tid = threadIdx.x;
    const int w = tid >> 6, lane = tid & 63;
    const int e = blockIdx.x * 4 + w;
    if (e >= EE) return;
    const int is = (e < E) ? src[e] : (e - E);
    const int id = (e < E) ? dst[e] : (e - E);
    float acc = 0.f;
    #pragma unroll
    for (int h = 0; h < HEADS; ++h) {
        const float alpha = score[(size_t)e * 4 + h] / denom[(size_t)id * 4 + h];
        acc += alpha * ld1(xl + (size_t)is * HC + h * CDIM + lane);
    }
    atomicAdd(&hagg[(size_t)id * CDIM + lane], acc * 0.25f);
}

// ---------- batchnorm stats ----------
__global__ void bn_stats(const float* __restrict__ hagg, float* __restrict__ sums,
                         float* __restrict__ sumsq, int N) {
    __shared__ float ls[4][64], ls2[4][64];
    const int c = threadIdx.x & 63, r = threadIdx.x >> 6;
    float s = 0.f, s2 = 0.f;
    for (int n = blockIdx.x * 4 + r; n < N; n += gridDim.x * 4) {
        const float v = hagg[(size_t)n * CDIM + c];
        s += v; s2 += v * v;
    }
    ls[r][c] = s; ls2[r][c] = s2;
    __syncthreads();
    if (threadIdx.x < 64) {
        atomicAdd(&sums[c], ls[0][c] + ls[1][c] + ls[2][c] + ls[3][c]);
        atomicAdd(&sumsq[c], ls2[0][c] + ls2[1][c] + ls2[2][c] + ls2[3][c]);
    }
}

// ---------- bn + relu + concat l -> hcat [N,65] ----------
__global__ void bn_apply_cat(const float* __restrict__ hagg, const float* __restrict__ sums,
                             const float* __restrict__ sumsq,
                             const float* __restrict__ g, const float* __restrict__ be,
                             const float* __restrict__ l, float* __restrict__ hcat, int N) {
    const long gid = (long)blockIdx.x * 256 + threadIdx.x;
    if (gid >= (long)N * CDIM) return;
    const int n = (int)(gid >> 6), c = (int)(gid & 63);
    const float inv = 1.0f / (float)N;
    const float mu = sums[c] * inv;
    const float var = sumsq[c] * inv - mu * mu;
    const float rs = rsqrtf(var + BN_EPS);
    const float z = fmaxf(0.f, (hagg[gid] - mu) * rs * g[c] + be[c]);
    hcat[(size_t)n * 65 + c] = z;
    if (c == 0) hcat[(size_t)n * 65 + 64] = l[n];
}

// ---------- bn + relu + column sum (layer 2 epilogue) ----------
__global__ void bn_reduce_z(const float* __restrict__ hagg, const float* __restrict__ sums,
                            const float* __restrict__ sumsq,
                            const float* __restrict__ g, const float* __restrict__ be,
                            float* __restrict__ zbar, int N) {
    __shared__ float ls[4][64];
    const int c = threadIdx.x & 63, r = threadIdx.x >> 6;
    const float inv = 1.0f / (float)N;
    const float mu = sums[c] * inv;
    const float var = sumsq[c] * inv - mu * mu;
    const float rs = rsqrtf(var + BN_EPS);
    const float gg = g[c], bb = be[c];
    float s = 0.f;
    for (int n = blockIdx.x * 4 + r; n < N; n += gridDim.x * 4) {
        const float v = hagg[(size_t)n * CDIM + c];
        s += fmaxf(0.f, (v - mu) * rs * gg + bb);
    }
    ls[r][c] = s;
    __syncthreads();
    if (threadIdx.x < 64) atomicAdd(&zbar[c], ls[0][c] + ls[1][c] + ls[2][c] + ls[3][c]);
}

// ---------- out[j] = (zbar/N) @ Wlin + blin ----------
__global__ void final_kernel(const float* __restrict__ zbar, const float* __restrict__ Wlin,
                             const float* __restrict__ blin, float* __restrict__ out, int N) {
    const int j = threadIdx.x;  // 128 threads
    float acc = blin[j];
    const float inv = 1.0f / (float)N;
    for (int c = 0; c < CDIM; ++c) acc += (zbar[c] * inv) * Wlin[(size_t)c * 128 + j];
    out[j] = acc;
}

template <typename TS>
static void run_all(const float* x, const int* src, const int* dst, const float* l,
                    const float* Wl1, const float* Wr1, const float* att1,
                    const float* g1, const float* be1,
                    const float* Wl2, const float* Wr2, const float* att2,
                    const float* g2, const float* be2,
                    const float* Wlin, const float* blin, float* out,
                    int N, int E, void* d_ws, hipStream_t stream) {
    const int EE = E + N;

    char* p = (char*)d_ws;
    TS* xl = (TS*)p;            p += (size_t)N * HC * sizeof(TS);
    TS* xr = (TS*)p;            p += (size_t)N * HC * sizeof(TS);
    float* score = (float*)p;   p += (size_t)EE * 4 * sizeof(float);
    unsigned* m = (unsigned*)p; p += (size_t)N * 4 * sizeof(unsigned);
    float* denom = (float*)p;   p += (size_t)N * 4 * sizeof(float);
    float* hagg = (float*)p;    p += (size_t)N * CDIM * sizeof(float);
    float* hcat = (float*)p;    p += (size_t)N * 65 * sizeof(float);
    float* sums = (float*)p;    p += 64 * sizeof(float);
    float* sumsq = (float*)p;   p += 64 * sizeof(float);
    float* zbar = (float*)p;    p += 64 * sizeof(float);

    const int edgeBlocks = (EE + 3) / 4;
    const int expvBlocks = (int)(((long)EE * 4 + 255) / 256);
    const int bnBlocks = 256;
    const int applyBlocks = (int)(((long)N * CDIM + 255) / 256);

    // ===== Layer 1 =====
    hipMemsetAsync(m, 0, (size_t)N * 4 * sizeof(unsigned), stream);
    hipMemsetAsync(denom, 0, (size_t)N * 4 * sizeof(float), stream);
    hipMemsetAsync(hagg, 0, (size_t)N * CDIM * sizeof(float), stream);
    hipMemsetAsync(sums, 0, 3 * 64 * sizeof(float), stream);  // sums+sumsq+zbar

    gemm_xlxr<TS><<<N, 256, 0, stream>>>(x, 32, 32, Wl1, Wr1, xl, xr);
    score_kernel<TS><<<edgeBlocks, 256, 0, stream>>>(xl, xr, src, dst, att1, score, m, E, EE);
    expv_kernel<<<expvBlocks, 256, 0, stream>>>(score, m, denom, dst, E, EE);
    agg_kernel<TS><<<edgeBlocks, 256, 0, stream>>>(xl, score, denom, src, dst, hagg, E, EE);
    bn_stats<<<bnBlocks, 256, 0, stream>>>(hagg, sums, sumsq, N);
    bn_apply_cat<<<applyBlocks, 256, 0, stream>>>(hagg, sums, sumsq, g1, be1, l, hcat, N);

    // ===== Layer 2 =====
    hipMemsetAsync(m, 0, (size_t)N * 4 * sizeof(unsigned), stream);
    hipMemsetAsync(denom, 0, (size_t)N * 4 * sizeof(float), stream);
    hipMemsetAsync(hagg, 0, (size_t)N * CDIM * sizeof(float), stream);
    hipMemsetAsync(sums, 0, 2 * 64 * sizeof(float), stream);  // sums+sumsq

    gemm_xlxr<TS><<<N, 256, 0, stream>>>(hcat, 65, 65, Wl2, Wr2, xl, xr);
    score_kernel<TS><<<edgeBlocks, 256, 0, stream>>>(xl, xr, src, dst, att2, score, m, E, EE);
    expv_kernel<<<expvBlocks, 256, 0, stream>>>(score, m, denom, dst, E, EE);
    agg_kernel<TS><<<edgeBlocks, 256, 0, stream>>>(xl, score, denom, src, dst, hagg, E, EE);
    bn_stats<<<bnBlocks, 256, 0, stream>>>(hagg, sums, sumsq, N);
    bn_reduce_z<<<bnBlocks, 256, 0, stream>>>(hagg, sums, sumsq, g2, be2, zbar, N);

    final_kernel<<<1, 128, 0, stream>>>(zbar, Wlin, blin, out, N);
}

extern "C" void kernel_launch(void* const* d_in, const int* in_sizes, int n_in,
                              void* d_out, int out_size, void* d_ws, size_t ws_size,
                              hipStream_t stream) {
    const float* x    = (const float*)d_in[0];
    const int*   ei   = (const int*)d_in[1];
    const float* l    = (const float*)d_in[2];
    const float* Wl1  = (const float*)d_in[3];
    const float* Wr1  = (const float*)d_in[4];
    const float* att1 = (const float*)d_in[5];
    const float* g1   = (const float*)d_in[7];
    const float* be1  = (const float*)d_in[8];
    const float* Wl2  = (const float*)d_in[9];
    const float* Wr2  = (const float*)d_in[10];
    const float* att2 = (const float*)d_in[11];
    const float* g2   = (const float*)d_in[13];
    const float* be2  = (const float*)d_in[14];
    const float* Wlin = (const float*)d_in[15];
    const float* blin = (const float*)d_in[16];
    float* out = (float*)d_out;

    const int N = in_sizes[2];       // 50000
    const int E = in_sizes[1] / 2;   // 400000
    const int EE = E + N;
    const int* src = ei;
    const int* dst = ei + E;

    // workspace need: f32 path keeps xl/xr in f32 (~137 MB); otherwise bf16 (~85 MB)
    const size_t fixed = (size_t)EE * 4 * 4 + (size_t)N * 4 * 4 * 2 +
                         (size_t)N * CDIM * 4 + (size_t)N * 65 * 4 + 3 * 64 * 4;
    const size_t need_f32 = fixed + 2 * (size_t)N * HC * sizeof(float);

    if (ws_size >= need_f32) {
        run_all<float>(x, src, dst, l, Wl1, Wr1, att1, g1, be1,
                       Wl2, Wr2, att2, g2, be2, Wlin, blin, out, N, E, d_ws, stream);
    } else {
        run_all<bf16>(x, src, dst, l, Wl1, Wr1, att1, g1, be1,
                      Wl2, Wr2, att2, g2, be2, Wlin, blin, out, N, E, d_ws, stream);
    }
}

// Round 3
// 644.864 us; speedup vs baseline: 1.4054x; 1.4054x over previous
//
#include <hip/hip_runtime.h>
#include <hip/hip_bf16.h>

typedef __hip_bfloat16 bf16;
typedef unsigned short u16;

#define NEG 0.2f
#define BN_EPS 1e-5f
#define GROWS 128
#define GCHUNK 16

__device__ __forceinline__ float u2f(u16 u) { return __uint_as_float(((unsigned)u) << 16); }
__device__ __forceinline__ u16 f2b(float f) { bf16 t = __float2bfloat16(f); return *(u16*)&t; }
__device__ __forceinline__ float leaky(float x) { return x > 0.f ? x : NEG * x; }

// ================= GEMM layer 1: xl|xr = X @ (Wl|Wr), bf16 out =================
// 512 threads: t<256 -> Wl col t, t>=256 -> Wr col t-256. Weights in registers.
template <int K, int KP>
__global__ __launch_bounds__(512) void gemm1_kernel(
    const float* __restrict__ X,
    const float* __restrict__ Wl, const float* __restrict__ Wr,
    u16* __restrict__ xl, u16* __restrict__ xr, int N) {
    const int col = threadIdx.x & 255;
    const int sel = threadIdx.x >> 8;
    const float* __restrict__ W = sel ? Wr : Wl;
    u16* __restrict__ out = sel ? xr : xl;

    float w[KP];
    #pragma unroll
    for (int k = 0; k < KP; ++k) w[k] = (k < K) ? W[(size_t)k * 256 + col] : 0.f;

    __shared__ float xs[GCHUNK][KP];
    const int row0 = blockIdx.x * GROWS;

    for (int c0 = 0; c0 < GROWS; c0 += GCHUNK) {
        const int rbase = row0 + c0;
        if (rbase >= N) break;
        __syncthreads();
        for (int idx = threadIdx.x; idx < GCHUNK * KP; idx += 512) {
            const int r = idx / KP, k = idx - r * KP;
            const int rr = rbase + r;
            xs[r][k] = (rr < N && k < K) ? X[(size_t)rr * K + k] : 0.f;
        }
        __syncthreads();
        for (int r = 0; r < GCHUNK; ++r) {
            const int rr = rbase + r;
            if (rr >= N) break;
            float sx = 0.f, sy = 0.f, sz = 0.f, sw = 0.f;
            #pragma unroll
            for (int k4 = 0; k4 < KP; k4 += 4) {
                const float4 xv = *reinterpret_cast<const float4*>(&xs[r][k4]);
                sx += xv.x * w[k4];
                sy += xv.y * w[k4 + 1];
                sz += xv.z * w[k4 + 2];
                sw += xv.w * w[k4 + 3];
            }
            out[(size_t)rr * 256 + col] = f2b((sx + sy) + (sz + sw));
        }
    }
}

// ===== GEMM layer 2: input = [relu(bn(hagg)) | l] (fused), bf16 out =====
template <int K, int KP>
__global__ __launch_bounds__(512) void gemm2_kernel(
    const float* __restrict__ hagg, const float* __restrict__ sums,
    const float* __restrict__ sumsq, const float* __restrict__ g,
    const float* __restrict__ be, const float* __restrict__ l,
    const float* __restrict__ Wl, const float* __restrict__ Wr,
    u16* __restrict__ xl, u16* __restrict__ xr, int N) {
    const int col = threadIdx.x & 255;
    const int sel = threadIdx.x >> 8;
    const float* __restrict__ W = sel ? Wr : Wl;
    u16* __restrict__ out = sel ? xr : xl;

    __shared__ float sc[64], sh[64];
    if (threadIdx.x < 64) {
        const int c = threadIdx.x;
        const float invN = 1.0f / (float)N;
        const float mu = sums[c] * invN;
        const float var = sumsq[c] * invN - mu * mu;
        const float s = rsqrtf(var + BN_EPS) * g[c];
        sc[c] = s;
        sh[c] = be[c] - mu * s;
    }

    float w[KP];
    #pragma unroll
    for (int k = 0; k < KP; ++k) w[k] = (k < K) ? W[(size_t)k * 256 + col] : 0.f;

    __shared__ float xs[GCHUNK][KP];
    const int row0 = blockIdx.x * GROWS;
    __syncthreads();  // sc/sh ready

    for (int c0 = 0; c0 < GROWS; c0 += GCHUNK) {
        const int rbase = row0 + c0;
        if (rbase >= N) break;
        __syncthreads();
        for (int idx = threadIdx.x; idx < GCHUNK * KP; idx += 512) {
            const int r = idx / KP, k = idx - r * KP;
            const int rr = rbase + r;
            float v = 0.f;
            if (rr < N) {
                if (k < 64)       v = fmaxf(0.f, hagg[(size_t)rr * 64 + k] * sc[k] + sh[k]);
                else if (k == 64) v = l[rr];
            }
            xs[r][k] = v;
        }
        __syncthreads();
        for (int r = 0; r < GCHUNK; ++r) {
            const int rr = rbase + r;
            if (rr >= N) break;
            float sx = 0.f, sy = 0.f, sz = 0.f, sw = 0.f;
            #pragma unroll
            for (int k4 = 0; k4 < KP; k4 += 4) {
                const float4 xv = *reinterpret_cast<const float4*>(&xs[r][k4]);
                sx += xv.x * w[k4];
                sy += xv.y * w[k4 + 1];
                sz += xv.z * w[k4 + 2];
                sw += xv.w * w[k4 + 3];
            }
            out[(size_t)rr * 256 + col] = f2b((sx + sy) + (sz + sw));
        }
    }
}

// ===== edge scores: exp(att . leaky(xl[src]+xr[dst])) + denom atomics =====
__global__ void score_kernel(const u16* __restrict__ xl, const u16* __restrict__ xr,
                             const int* __restrict__ src, const int* __restrict__ dst,
                             const float* __restrict__ att,
                             float* __restrict__ expv, float* __restrict__ denom,
                             int E, int EE) {
    const int w = threadIdx.x >> 6, lane = threadIdx.x & 63;
    const float4 av = reinterpret_cast<const float4*>(att)[lane];
    const int step = gridDim.x * 4;
    for (int e = blockIdx.x * 4 + w; e < EE; e += step) {
        const int is = (e < E) ? src[e] : (e - E);
        const int id = (e < E) ? dst[e] : (e - E);
        const ushort4 a = reinterpret_cast<const ushort4*>(xl + (size_t)is * 256)[lane];
        const ushort4 b = reinterpret_cast<const ushort4*>(xr + (size_t)id * 256)[lane];
        float p = av.x * leaky(u2f(a.x) + u2f(b.x)) + av.y * leaky(u2f(a.y) + u2f(b.y))
                + av.z * leaky(u2f(a.z) + u2f(b.z)) + av.w * leaky(u2f(a.w) + u2f(b.w));
        #pragma unroll
        for (int o = 8; o; o >>= 1) p += __shfl_xor(p, o);
        if ((lane & 15) == 0) {
            const int h = lane >> 4;
            const float ev = __expf(p);
            expv[(size_t)e * 4 + h] = ev;
            atomicAdd(&denom[(size_t)id * 4 + h], ev);
        }
    }
}

// ===== aggregation: hagg[dst,c] += 0.25 * sum_h alpha_eh * xl[src,h*64+c] =====
__global__ void agg_kernel(const u16* __restrict__ xl, const float* __restrict__ expv,
                           const float* __restrict__ denom,
                           const int* __restrict__ src, const int* __restrict__ dst,
                           float* __restrict__ hagg, int E, int EE) {
    const int w = threadIdx.x >> 6, lane = threadIdx.x & 63;
    const int step = gridDim.x * 4;
    for (int e = blockIdx.x * 4 + w; e < EE; e += step) {
        const int is = (e < E) ? src[e] : (e - E);
        const int id = (e < E) ? dst[e] : (e - E);
        const float4 ev = *reinterpret_cast<const float4*>(expv + (size_t)e * 4);
        const float4 dn = *reinterpret_cast<const float4*>(denom + (size_t)id * 4);
        const u16* row = xl + (size_t)is * 256;
        float acc = (ev.x / dn.x) * u2f(row[lane])
                  + (ev.y / dn.y) * u2f(row[64 + lane])
                  + (ev.z / dn.z) * u2f(row[128 + lane])
                  + (ev.w / dn.w) * u2f(row[192 + lane]);
        atomicAdd(&hagg[(size_t)id * 64 + lane], acc * 0.25f);
    }
}

// ===== batchnorm stats =====
__global__ void bn_stats(const float* __restrict__ hagg, float* __restrict__ sums,
                         float* __restrict__ sumsq, int N) {
    __shared__ float ls[4][64], ls2[4][64];
    const int c = threadIdx.x & 63, r = threadIdx.x >> 6;
    float s = 0.f, s2 = 0.f;
    for (int n = blockIdx.x * 4 + r; n < N; n += gridDim.x * 4) {
        const float v = hagg[(size_t)n * 64 + c];
        s += v; s2 += v * v;
    }
    ls[r][c] = s; ls2[r][c] = s2;
    __syncthreads();
    if (threadIdx.x < 64) {
        atomicAdd(&sums[c], ls[0][c] + ls[1][c] + ls[2][c] + ls[3][c]);
        atomicAdd(&sumsq[c], ls2[0][c] + ls2[1][c] + ls2[2][c] + ls2[3][c]);
    }
}

// ===== bn + relu + column sum (layer 2 epilogue) =====
__global__ void bn_reduce_z(const float* __restrict__ hagg, const float* __restrict__ sums,
                            const float* __restrict__ sumsq,
                            const float* __restrict__ g, const float* __restrict__ be,
                            float* __restrict__ zbar, int N) {
    __shared__ float ls[4][64];
    const int c = threadIdx.x & 63, r = threadIdx.x >> 6;
    const float invN = 1.0f / (float)N;
    const float mu = sums[c] * invN;
    const float var = sumsq[c] * invN - mu * mu;
    const float rs = rsqrtf(var + BN_EPS);
    const float gg = g[c], bb = be[c];
    float s = 0.f;
    for (int n = blockIdx.x * 4 + r; n < N; n += gridDim.x * 4) {
        s += fmaxf(0.f, (hagg[(size_t)n * 64 + c] - mu) * rs * gg + bb);
    }
    ls[r][c] = s;
    __syncthreads();
    if (threadIdx.x < 64) atomicAdd(&zbar[c], ls[0][c] + ls[1][c] + ls[2][c] + ls[3][c]);
}

// ===== out[j] = (zbar/N) @ Wlin + blin =====
__global__ void final_kernel(const float* __restrict__ zbar, const float* __restrict__ Wlin,
                             const float* __restrict__ blin, float* __restrict__ out, int N) {
    const int j = threadIdx.x;  // 128
    float acc = blin[j];
    const float invN = 1.0f / (float)N;
    for (int c = 0; c < 64; ++c) acc += (zbar[c] * invN) * Wlin[(size_t)c * 128 + j];
    out[j] = acc;
}

extern "C" void kernel_launch(void* const* d_in, const int* in_sizes, int n_in,
                              void* d_out, int out_size, void* d_ws, size_t ws_size,
                              hipStream_t stream) {
    const float* x    = (const float*)d_in[0];
    const int*   ei   = (const int*)d_in[1];
    const float* l    = (const float*)d_in[2];
    const float* Wl1  = (const float*)d_in[3];
    const float* Wr1  = (const float*)d_in[4];
    const float* att1 = (const float*)d_in[5];
    const float* g1   = (const float*)d_in[7];
    const float* be1  = (const float*)d_in[8];
    const float* Wl2  = (const float*)d_in[9];
    const float* Wr2  = (const float*)d_in[10];
    const float* att2 = (const float*)d_in[11];
    const float* g2   = (const float*)d_in[13];
    const float* be2  = (const float*)d_in[14];
    const float* Wlin = (const float*)d_in[15];
    const float* blin = (const float*)d_in[16];
    float* out = (float*)d_out;

    const int N = in_sizes[2];       // 50000
    const int E = in_sizes[1] / 2;   // 400000
    const int EE = E + N;
    const int* src = ei;
    const int* dst = ei + E;

    // workspace carve (~72 MB); denom+hagg+zbar contiguous for one-shot memset
    char* p = (char*)d_ws;
    u16* xl = (u16*)p;          p += (size_t)N * 256 * sizeof(u16);
    u16* xr = (u16*)p;          p += (size_t)N * 256 * sizeof(u16);
    float* expv = (float*)p;    p += (size_t)EE * 4 * sizeof(float);
    float* denom = (float*)p;   p += (size_t)N * 4 * sizeof(float);
    float* hagg = (float*)p;    p += (size_t)N * 64 * sizeof(float);
    float* zbar = (float*)p;    p += 64 * sizeof(float);
    float* sums = (float*)p;    p += 64 * sizeof(float);
    float* sumsq = (float*)p;   p += 64 * sizeof(float);

    const size_t dh_bytes = (size_t)N * 4 * sizeof(float) + (size_t)N * 64 * sizeof(float);

    const int gemmBlocks = (N + GROWS - 1) / GROWS;
    const int edgeBlocks = 2048;
    const int bnBlocks = 256;

    // ===== Layer 1 =====
    hipMemsetAsync(denom, 0, dh_bytes + 3 * 64 * sizeof(float), stream);  // denom+hagg+zbar+sums+sumsq
    gemm1_kernel<32, 32><<<gemmBlocks, 512, 0, stream>>>(x, Wl1, Wr1, xl, xr, N);
    score_kernel<<<edgeBlocks, 256, 0, stream>>>(xl, xr, src, dst, att1, expv, denom, E, EE);
    agg_kernel<<<edgeBlocks, 256, 0, stream>>>(xl, expv, denom, src, dst, hagg, E, EE);
    bn_stats<<<bnBlocks, 256, 0, stream>>>(hagg, sums, sumsq, N);

    // ===== Layer 2 (bn+relu+concat fused into gemm2 staging) =====
    gemm2_kernel<65, 68><<<gemmBlocks, 512, 0, stream>>>(hagg, sums, sumsq, g1, be1, l,
                                                         Wl2, Wr2, xl, xr, N);
    hipMemsetAsync(denom, 0, dh_bytes, stream);  // after gemm2 consumed hagg
    hipMemsetAsync(sums, 0, 2 * 64 * sizeof(float), stream);
    score_kernel<<<edgeBlocks, 256, 0, stream>>>(xl, xr, src, dst, att2, expv, denom, E, EE);
    agg_kernel<<<edgeBlocks, 256, 0, stream>>>(xl, expv, denom, src, dst, hagg, E, EE);
    bn_stats<<<bnBlocks, 256, 0, stream>>>(hagg, sums, sumsq, N);
    bn_reduce_z<<<bnBlocks, 256, 0, stream>>>(hagg, sums, sumsq, g2, be2, zbar, N);

    final_kernel<<<1, 128, 0, stream>>>(zbar, Wlin, blin, out, N);
}

// Round 4
// 477.820 us; speedup vs baseline: 1.8967x; 1.3496x over previous
//
#include <hip/hip_runtime.h>
#include <hip/hip_bf16.h>

typedef __hip_bfloat16 bf16;
typedef unsigned short u16;

#define NEG 0.2f
#define BN_EPS 1e-5f
#define GROWS 32

__device__ __forceinline__ float u2f(u16 u) { return __uint_as_float(((unsigned)u) << 16); }
__device__ __forceinline__ u16 f2b(float f) { bf16 t = __float2bfloat16(f); return *(u16*)&t; }
__device__ __forceinline__ float leaky(float x) { return x > 0.f ? x : NEG * x; }

// ================= GEMM: xl|xr = X @ (Wl|Wr), bf16 out =================
// 512 threads: t<256 -> Wl col t, t>=256 -> Wr col t-256. Weights in VGPRs,
// x-row values are wave-uniform (scalar loads) -> no LDS in the inner loop.
template <int K>
__global__ __launch_bounds__(512) void gemm_kernel(
    const float* __restrict__ X, int ldx,
    const float* __restrict__ Wl, const float* __restrict__ Wr,
    u16* __restrict__ xl, u16* __restrict__ xr, int N) {
    const int col = threadIdx.x & 255;
    const int sel = threadIdx.x >> 8;
    const float* __restrict__ W = sel ? Wr : Wl;
    u16* __restrict__ out = sel ? xr : xl;

    float w[K];
    #pragma unroll
    for (int k = 0; k < K; ++k) w[k] = W[(size_t)k * 256 + col];

    const int row0 = blockIdx.x * GROWS;
    const int rowEnd = min(row0 + GROWS, N);
    for (int r = row0; r < rowEnd; ++r) {
        const float* __restrict__ xp = X + (size_t)r * ldx;  // block-uniform base
        float acc[4] = {0.f, 0.f, 0.f, 0.f};
        #pragma unroll
        for (int k = 0; k < K; ++k) acc[k & 3] += xp[k] * w[k];
        out[(size_t)r * 256 + col] = f2b((acc[0] + acc[1]) + (acc[2] + acc[3]));
    }
}

// ===== fused GAT: per dst node, score+softmax+aggregate in registers =====
__global__ void gat_fused(const u16* __restrict__ xl, const u16* __restrict__ xr,
                          const int* __restrict__ csr_src, const int* __restrict__ offs,
                          const float* __restrict__ att,
                          float* __restrict__ hagg, int N) {
    const int wv = threadIdx.x >> 6, lane = threadIdx.x & 63;
    const int id = blockIdx.x * 4 + wv;
    if (id >= N) return;
    const float4 av = reinterpret_cast<const float4*>(att)[lane];

    const ushort4 b = reinterpret_cast<const ushort4*>(xr + (size_t)id * 256)[lane];
    const float bx = u2f(b.x), by = u2f(b.y), bz = u2f(b.z), bw = u2f(b.w);

    float ax0 = 0.f, ax1 = 0.f, ax2 = 0.f, ax3 = 0.f;  // sum ev * xl
    float denom = 0.f;                                  // per-head (uniform in 16-group)

    const int e0 = offs[id], e1 = offs[id + 1];
    int e = e0 - 1;  // e0-1 encodes the self-loop iteration
    for (; e < e1; ++e) {
        const int s = (e < e0) ? id : csr_src[e];
        const ushort4 a = reinterpret_cast<const ushort4*>(xl + (size_t)s * 256)[lane];
        const float x0 = u2f(a.x), x1 = u2f(a.y), x2 = u2f(a.z), x3 = u2f(a.w);
        float p = av.x * leaky(x0 + bx) + av.y * leaky(x1 + by)
                + av.z * leaky(x2 + bz) + av.w * leaky(x3 + bw);
        p += __shfl_xor(p, 1);
        p += __shfl_xor(p, 2);
        p += __shfl_xor(p, 4);
        p += __shfl_xor(p, 8);   // all 16 lanes of the head group hold the score
        const float ev = __expf(p);
        denom += ev;
        ax0 += ev * x0; ax1 += ev * x1; ax2 += ev * x2; ax3 += ev * x3;
    }

    const float s = 0.25f / denom;   // head-mean folded in
    float r0 = ax0 * s, r1 = ax1 * s, r2 = ax2 * s, r3 = ax3 * s;
    // sum across the 4 head groups (lanes q, q+16, q+32, q+48)
    r0 += __shfl_xor(r0, 16); r0 += __shfl_xor(r0, 32);
    r1 += __shfl_xor(r1, 16); r1 += __shfl_xor(r1, 32);
    r2 += __shfl_xor(r2, 16); r2 += __shfl_xor(r2, 32);
    r3 += __shfl_xor(r3, 16); r3 += __shfl_xor(r3, 32);
    if (lane < 16) {
        float4 o = make_float4(r0, r1, r2, r3);
        *reinterpret_cast<float4*>(hagg + (size_t)id * 64 + lane * 4) = o;
    }
}

// ===== CSR build =====
__global__ void hist_kernel(const int* __restrict__ dst, int* __restrict__ deg, int E) {
    for (int e = blockIdx.x * 256 + threadIdx.x; e < E; e += gridDim.x * 256)
        atomicAdd(&deg[dst[e]], 1);
}

__global__ __launch_bounds__(1024) void scan1(const int* __restrict__ deg,
                                              int* __restrict__ offs,
                                              int* __restrict__ part, int N) {
    const int i = blockIdx.x * 1024 + threadIdx.x;
    const int lane = threadIdx.x & 63, wid = threadIdx.x >> 6;
    const int v = (i < N) ? deg[i] : 0;
    int s = v;
    #pragma unroll
    for (int o = 1; o < 64; o <<= 1) { int t = __shfl_up(s, o); if (lane >= o) s += t; }
    __shared__ int wt[16];
    if (lane == 63) wt[wid] = s;
    __syncthreads();
    if (threadIdx.x < 16) {
        int t = wt[threadIdx.x];
        #pragma unroll
        for (int o = 1; o < 16; o <<= 1) { int u = __shfl_up(t, o); if (threadIdx.x >= o) t += u; }
        wt[threadIdx.x] = t;
    }
    __syncthreads();
    const int incl = s + (wid > 0 ? wt[wid - 1] : 0);
    if (i < N) offs[i] = incl - v;            // intra-block exclusive
    if (threadIdx.x == 1023) part[blockIdx.x] = incl;  // block total
}

__global__ void scan2(int* __restrict__ part, int nb) {
    if (nb <= 64) {
        const int lane = threadIdx.x;
        int v = (lane < nb) ? part[lane] : 0;
        int s = v;
        #pragma unroll
        for (int o = 1; o < 64; o <<= 1) { int t = __shfl_up(s, o); if (lane >= o) s += t; }
        if (lane < nb) part[lane] = s - v;    // exclusive
    } else if (threadIdx.x == 0) {
        int run = 0;
        for (int b = 0; b < nb; ++b) { int t = part[b]; part[b] = run; run += t; }
    }
}

__global__ __launch_bounds__(1024) void scan3(int* __restrict__ offs,
                                              const int* __restrict__ part, int N, int E) {
    const int i = blockIdx.x * 1024 + threadIdx.x;
    if (i < N) offs[i] += part[blockIdx.x];
    if (i == 0) offs[N] = E;
}

__global__ void scatter_kernel(const int* __restrict__ src, const int* __restrict__ dst,
                               int* __restrict__ cursor, int* __restrict__ csr_src, int E) {
    for (int e = blockIdx.x * 256 + threadIdx.x; e < E; e += gridDim.x * 256) {
        const int p = atomicAdd(&cursor[dst[e]], 1);
        csr_src[p] = src[e];
    }
}

// ===== batchnorm stats =====
__global__ void bn_stats(const float* __restrict__ hagg, float* __restrict__ sums,
                         float* __restrict__ sumsq, int N) {
    __shared__ float ls[4][64], ls2[4][64];
    const int c = threadIdx.x & 63, r = threadIdx.x >> 6;
    float s = 0.f, s2 = 0.f;
    for (int n = blockIdx.x * 4 + r; n < N; n += gridDim.x * 4) {
        const float v = hagg[(size_t)n * 64 + c];
        s += v; s2 += v * v;
    }
    ls[r][c] = s; ls2[r][c] = s2;
    __syncthreads();
    if (threadIdx.x < 64) {
        atomicAdd(&sums[c], ls[0][c] + ls[1][c] + ls[2][c] + ls[3][c]);
        atomicAdd(&sumsq[c], ls2[0][c] + ls2[1][c] + ls2[2][c] + ls2[3][c]);
    }
}

// ===== bn + relu + concat l -> hcat [N,65] f32 =====
__global__ void bn_apply_cat(const float* __restrict__ hagg, const float* __restrict__ sums,
                             const float* __restrict__ sumsq,
                             const float* __restrict__ g, const float* __restrict__ be,
                             const float* __restrict__ l, float* __restrict__ hcat, int N) {
    const int t = threadIdx.x;           // 260 = 4 nodes x 65
    const int n = blockIdx.x * 4 + t / 65;
    const int c = t % 65;
    if (n >= N) return;
    if (c < 64) {
        const float invN = 1.0f / (float)N;
        const float mu = sums[c] * invN;
        const float var = sumsq[c] * invN - mu * mu;
        const float sc = rsqrtf(var + BN_EPS) * g[c];
        hcat[(size_t)n * 65 + c] = fmaxf(0.f, (hagg[(size_t)n * 64 + c] - mu) * sc + (be[c] - mu * 0.f) - mu * sc + mu * sc) ;
    } else {
        hcat[(size_t)n * 65 + 64] = l[n];
    }
}

// (clean version of the bn transform to avoid the expression mess above)
__global__ void bn_apply_cat2(const float* __restrict__ hagg, const float* __restrict__ sums,
                              const float* __restrict__ sumsq,
                              const float* __restrict__ g, const float* __restrict__ be,
                              const float* __restrict__ l, float* __restrict__ hcat, int N) {
    const int t = threadIdx.x;
    const int n = blockIdx.x * 4 + t / 65;
    const int c = t % 65;
    if (n >= N) return;
    if (c < 64) {
        const float invN = 1.0f / (float)N;
        const float mu = sums[c] * invN;
        const float var = sumsq[c] * invN - mu * mu;
        const float sc = rsqrtf(var + BN_EPS) * g[c];
        const float sh = be[c] - mu * sc;
        hcat[(size_t)n * 65 + c] = fmaxf(0.f, hagg[(size_t)n * 64 + c] * sc + sh);
    } else {
        hcat[(size_t)n * 65 + 64] = l[n];
    }
}

// ===== bn + relu + column sum (layer 2 epilogue) =====
__global__ void bn_reduce_z(const float* __restrict__ hagg, const float* __restrict__ sums,
                            const float* __restrict__ sumsq,
                            const float* __restrict__ g, const float* __restrict__ be,
                            float* __restrict__ zbar, int N) {
    __shared__ float ls[4][64];
    const int c = threadIdx.x & 63, r = threadIdx.x >> 6;
    const float invN = 1.0f / (float)N;
    const float mu = sums[c] * invN;
    const float var = sumsq[c] * invN - mu * mu;
    const float rs = rsqrtf(var + BN_EPS);
    const float gg = g[c], bb = be[c];
    float s = 0.f;
    for (int n = blockIdx.x * 4 + r; n < N; n += gridDim.x * 4) {
        s += fmaxf(0.f, (hagg[(size_t)n * 64 + c] - mu) * rs * gg + bb);
    }
    ls[r][c] = s;
    __syncthreads();
    if (threadIdx.x < 64) atomicAdd(&zbar[c], ls[0][c] + ls[1][c] + ls[2][c] + ls[3][c]);
}

// ===== out[j] = (zbar/N) @ Wlin + blin =====
__global__ void final_kernel(const float* __restrict__ zbar, const float* __restrict__ Wlin,
                             const float* __restrict__ blin, float* __restrict__ out, int N) {
    const int j = threadIdx.x;  // 128
    float acc = blin[j];
    const float invN = 1.0f / (float)N;
    for (int c = 0; c < 64; ++c) acc += (zbar[c] * invN) * Wlin[(size_t)c * 128 + j];
    out[j] = acc;
}

static inline char* align16(char* p) {
    return (char*)(((uintptr_t)p + 15) & ~(uintptr_t)15);
}

extern "C" void kernel_launch(void* const* d_in, const int* in_sizes, int n_in,
                              void* d_out, int out_size, void* d_ws, size_t ws_size,
                              hipStream_t stream) {
    const float* x    = (const float*)d_in[0];
    const int*   ei   = (const int*)d_in[1];
    const float* l    = (const float*)d_in[2];
    const float* Wl1  = (const float*)d_in[3];
    const float* Wr1  = (const float*)d_in[4];
    const float* att1 = (const float*)d_in[5];
    const float* g1   = (const float*)d_in[7];
    const float* be1  = (const float*)d_in[8];
    const float* Wl2  = (const float*)d_in[9];
    const float* Wr2  = (const float*)d_in[10];
    const float* att2 = (const float*)d_in[11];
    const float* g2   = (const float*)d_in[13];
    const float* be2  = (const float*)d_in[14];
    const float* Wlin = (const float*)d_in[15];
    const float* blin = (const float*)d_in[16];
    float* out = (float*)d_out;

    const int N = in_sizes[2];       // 50000
    const int E = in_sizes[1] / 2;   // 400000
    const int* src = ei;
    const int* dst = ei + E;

    // workspace carve (~79 MB)
    char* p = (char*)d_ws;
    u16* xl = (u16*)p;          p += (size_t)N * 256 * sizeof(u16);
    u16* xr = (u16*)p;          p += (size_t)N * 256 * sizeof(u16);
    float* hagg = (float*)p;    p += (size_t)N * 64 * sizeof(float);
    float* hcat = (float*)p;    p += (size_t)N * 65 * sizeof(float);  p = align16(p);
    int* csr_src = (int*)p;     p += (size_t)E * sizeof(int);
    int* deg = (int*)p;         p += (size_t)N * sizeof(int);
    int* offs = (int*)p;        p += (size_t)(N + 1) * sizeof(int);
    int* cursor = (int*)p;      p += (size_t)N * sizeof(int);
    int* part = (int*)p;        p += 256 * sizeof(int);
    float* sums = (float*)p;    p += 64 * sizeof(float);
    float* sumsq = (float*)p;   p += 64 * sizeof(float);
    float* zbar = (float*)p;    p += 64 * sizeof(float);

    const int gemmBlocks = (N + GROWS - 1) / GROWS;
    const int nodeBlocks = (N + 3) / 4;
    const int scanBlocks = (N + 1023) / 1024;
    const int bnBlocks = 256;

    // ===== CSR build (dst-sorted incoming edges) =====
    hipMemsetAsync(deg, 0, (size_t)N * sizeof(int), stream);
    hist_kernel<<<2048, 256, 0, stream>>>(dst, deg, E);
    scan1<<<scanBlocks, 1024, 0, stream>>>(deg, offs, part, N);
    scan2<<<1, 64, 0, stream>>>(part, scanBlocks);
    scan3<<<scanBlocks, 1024, 0, stream>>>(offs, part, N, E);
    hipMemcpyAsync(cursor, offs, (size_t)N * sizeof(int), hipMemcpyDeviceToDevice, stream);
    scatter_kernel<<<2048, 256, 0, stream>>>(src, dst, cursor, csr_src, E);

    hipMemsetAsync(sums, 0, 3 * 64 * sizeof(float), stream);  // sums+sumsq+zbar

    // ===== Layer 1 =====
    gemm_kernel<32><<<gemmBlocks, 512, 0, stream>>>(x, 32, Wl1, Wr1, xl, xr, N);
    gat_fused<<<nodeBlocks, 256, 0, stream>>>(xl, xr, csr_src, offs, att1, hagg, N);
    bn_stats<<<bnBlocks, 256, 0, stream>>>(hagg, sums, sumsq, N);
    bn_apply_cat2<<<nodeBlocks, 260, 0, stream>>>(hagg, sums, sumsq, g1, be1, l, hcat, N);

    // ===== Layer 2 =====
    gemm_kernel<65><<<gemmBlocks, 512, 0, stream>>>(hcat, 65, Wl2, Wr2, xl, xr, N);
    hipMemsetAsync(sums, 0, 2 * 64 * sizeof(float), stream);  // after bn_apply_cat2 read them
    gat_fused<<<nodeBlocks, 256, 0, stream>>>(xl, xr, csr_src, offs, att2, hagg, N);
    bn_stats<<<bnBlocks, 256, 0, stream>>>(hagg, sums, sumsq, N);
    bn_reduce_z<<<bnBlocks, 256, 0, stream>>>(hagg, sums, sumsq, g2, be2, zbar, N);

    final_kernel<<<1, 128, 0, stream>>>(zbar, Wlin, blin, out, N);
}

// Round 5
// 300.147 us; speedup vs baseline: 3.0195x; 1.5920x over previous
//
#include <hip/hip_runtime.h>
#include <hip/hip_bf16.h>

typedef __hip_bfloat16 bf16;
typedef unsigned short u16;

#define NEG 0.2f
#define BN_EPS 1e-5f

typedef __attribute__((ext_vector_type(8))) short bfrag;   // 8 bf16 = 4 VGPRs
typedef __attribute__((ext_vector_type(4))) float ffrag;   // 4 f32 acc

__device__ __forceinline__ float u2f(u16 u) { return __uint_as_float(((unsigned)u) << 16); }
__device__ __forceinline__ u16 f2b(float f) { bf16 t = __float2bfloat16(f); return *(u16*)&t; }
__device__ __forceinline__ float leaky(float x) { return x > 0.f ? x : NEG * x; }

// ===== W prep: swizzle (Wl|Wr) f32 [K][256]x2 into per-lane MFMA B-fragment order =====
// Wbf flat idx ((s*32 + ntile)*64 + lane)*8 + j  holds  W[k = s*32+(lane>>4)*8+j][ntile*16+(lane&15)]
__global__ void prep_w(const float* __restrict__ Wl, const float* __restrict__ Wr,
                       u16* __restrict__ Wbf, int K, int total) {
    const int idx = blockIdx.x * 256 + threadIdx.x;
    if (idx >= total) return;
    const int l = idx & 63, n = (idx >> 6) & 31, s = idx >> 11;
    const int col = n * 16 + (l & 15);
    const int kbase = s * 32 + ((l >> 4) << 3);
    const float* __restrict__ W = (col < 256) ? (Wl + col) : (Wr + col - 256);
    u16 v[8];
    #pragma unroll
    for (int j = 0; j < 8; ++j) {
        const int k = kbase + j;
        v[j] = (k < K) ? f2b(W[(size_t)k * 256]) : (u16)0;
    }
    ushort4* d = reinterpret_cast<ushort4*>(Wbf + (size_t)idx * 8);
    d[0] = make_ushort4(v[0], v[1], v[2], v[3]);
    d[1] = make_ushort4(v[4], v[5], v[6], v[7]);
}

// ===== MFMA GEMM: xl|xr = A @ (Wl|Wr).  A = X (STAGE 0) or [relu(bn(hagg))|l|0pad] (STAGE 1) =====
// 256 threads = 4 waves; 32 rows/block; wave w owns cols [w*128, w*128+128).
template <int KSTEPS, int STAGE>
__global__ __launch_bounds__(256) void gemm_mfma(
    const float* __restrict__ Xf,
    const float* __restrict__ hagg,
    const float* __restrict__ sums, const float* __restrict__ sumsq,
    const float* __restrict__ g, const float* __restrict__ be,
    const float* __restrict__ lf,
    const u16* __restrict__ Wbf,
    u16* __restrict__ xl, u16* __restrict__ xr, int N) {

    __shared__ u16 sA[32 * 104];      // A tile bf16, row stride 104 (bank-spread)
    __shared__ u16 sC[32 * 512];      // C tile bf16 for coalesced writeout
    __shared__ float ssc[64], ssh[64];

    const int tid = threadIdx.x;
    const int row0 = blockIdx.x * 32;

    if (STAGE == 1) {
        if (tid < 64) {
            const float invN = 1.0f / (float)N;
            const float mu = sums[tid] * invN;
            const float var = sumsq[tid] * invN - mu * mu;
            const float sc = rsqrtf(var + BN_EPS) * g[tid];
            ssc[tid] = sc;
            ssh[tid] = be[tid] - mu * sc;
        }
        __syncthreads();
        for (int idx = tid; idx < 32 * 24; idx += 256) {   // 96 padded cols
            const int r = idx / 24, c4 = (idx % 24) * 4;
            const int rr = row0 + r;
            float4 v = make_float4(0.f, 0.f, 0.f, 0.f);
            if (rr < N) {
                if (c4 < 64) {
                    const float4 hv = *reinterpret_cast<const float4*>(hagg + (size_t)rr * 64 + c4);
                    v.x = fmaxf(0.f, hv.x * ssc[c4]     + ssh[c4]);
                    v.y = fmaxf(0.f, hv.y * ssc[c4 + 1] + ssh[c4 + 1]);
                    v.z = fmaxf(0.f, hv.z * ssc[c4 + 2] + ssh[c4 + 2]);
                    v.w = fmaxf(0.f, hv.w * ssc[c4 + 3] + ssh[c4 + 3]);
                } else if (c4 == 64) {
                    v.x = lf[rr];
                }
            }
            *reinterpret_cast<ushort4*>(&sA[r * 104 + c4]) =
                make_ushort4(f2b(v.x), f2b(v.y), f2b(v.z), f2b(v.w));
        }
    } else {
        for (int idx = tid; idx < 32 * 8; idx += 256) {    // K=32
            const int r = idx >> 3, c4 = (idx & 7) * 4;
            const int rr = row0 + r;
            float4 v = make_float4(0.f, 0.f, 0.f, 0.f);
            if (rr < N) v = *reinterpret_cast<const float4*>(Xf + (size_t)rr * 32 + c4);
            *reinterpret_cast<ushort4*>(&sA[r * 104 + c4]) =
                make_ushort4(f2b(v.x), f2b(v.y), f2b(v.z), f2b(v.w));
        }
    }
    __syncthreads();

    const int w = tid >> 6, l = tid & 63;
    ffrag acc[2][8];
    #pragma unroll
    for (int m = 0; m < 2; ++m)
        #pragma unroll
        for (int n = 0; n < 8; ++n) acc[m][n] = ffrag{0.f, 0.f, 0.f, 0.f};

    #pragma unroll
    for (int s = 0; s < KSTEPS; ++s) {
        bfrag bf[8];
        #pragma unroll
        for (int n = 0; n < 8; ++n) {
            const int ntile = w * 8 + n;
            bf[n] = *reinterpret_cast<const bfrag*>(Wbf + ((size_t)(s * 32 + ntile) * 64 + l) * 8);
        }
        bfrag af[2];
        #pragma unroll
        for (int m = 0; m < 2; ++m) {
            const int off = (m * 16 + (l & 15)) * 104 + s * 32 + ((l >> 4) << 3);
            af[m] = *reinterpret_cast<const bfrag*>(&sA[off]);
        }
        #pragma unroll
        for (int n = 0; n < 8; ++n) {
            acc[0][n] = __builtin_amdgcn_mfma_f32_16x16x32_bf16(af[0], bf[n], acc[0][n], 0, 0, 0);
            acc[1][n] = __builtin_amdgcn_mfma_f32_16x16x32_bf16(af[1], bf[n], acc[1][n], 0, 0, 0);
        }
    }

    // acc -> sC (bf16).  C/D layout: col = lane&15, row = (lane>>4)*4 + j  [m89-verified]
    #pragma unroll
    for (int m = 0; m < 2; ++m)
        #pragma unroll
        for (int n = 0; n < 8; ++n) {
            const int col = w * 128 + n * 16 + (l & 15);
            const int rbase = m * 16 + ((l >> 4) << 2);
            #pragma unroll
            for (int j = 0; j < 4; ++j)
                sC[(rbase + j) * 512 + col] = f2b(acc[m][n][j]);
        }
    __syncthreads();

    for (int idx = tid; idx < 32 * 64; idx += 256) {
        const int r = idx >> 6, c8 = (idx & 63) * 8;
        const int rr = row0 + r;
        if (rr >= N) continue;
        const uint4 v = *reinterpret_cast<const uint4*>(&sC[r * 512 + c8]);
        if (c8 < 256)
            *reinterpret_cast<uint4*>(xl + (size_t)rr * 256 + c8) = v;
        else
            *reinterpret_cast<uint4*>(xr + (size_t)rr * 256 + (c8 - 256)) = v;
    }
}

// ===== fused GAT: per dst node, score+softmax+aggregate in registers =====
__global__ void gat_fused(const u16* __restrict__ xl, const u16* __restrict__ xr,
                          const int* __restrict__ csr_src, const int* __restrict__ offs,
                          const float* __restrict__ att,
                          float* __restrict__ hagg, int N) {
    const int wv = threadIdx.x >> 6, lane = threadIdx.x & 63;
    const int id = blockIdx.x * 4 + wv;
    if (id >= N) return;
    const float4 av = reinterpret_cast<const float4*>(att)[lane];

    const ushort4 b = reinterpret_cast<const ushort4*>(xr + (size_t)id * 256)[lane];
    const float bx = u2f(b.x), by = u2f(b.y), bz = u2f(b.z), bw = u2f(b.w);

    float ax0 = 0.f, ax1 = 0.f, ax2 = 0.f, ax3 = 0.f;
    float denom = 0.f;

    const int e0 = offs[id], e1 = offs[id + 1];
    for (int e = e0 - 1; e < e1; ++e) {        // e0-1 = self-loop iteration
        const int s = (e < e0) ? id : csr_src[e];
        const ushort4 a = reinterpret_cast<const ushort4*>(xl + (size_t)s * 256)[lane];
        const float x0 = u2f(a.x), x1 = u2f(a.y), x2 = u2f(a.z), x3 = u2f(a.w);
        float p = av.x * leaky(x0 + bx) + av.y * leaky(x1 + by)
                + av.z * leaky(x2 + bz) + av.w * leaky(x3 + bw);
        p += __shfl_xor(p, 1);
        p += __shfl_xor(p, 2);
        p += __shfl_xor(p, 4);
        p += __shfl_xor(p, 8);
        const float ev = __expf(p);
        denom += ev;
        ax0 += ev * x0; ax1 += ev * x1; ax2 += ev * x2; ax3 += ev * x3;
    }

    const float s = 0.25f / denom;
    float r0 = ax0 * s, r1 = ax1 * s, r2 = ax2 * s, r3 = ax3 * s;
    r0 += __shfl_xor(r0, 16); r0 += __shfl_xor(r0, 32);
    r1 += __shfl_xor(r1, 16); r1 += __shfl_xor(r1, 32);
    r2 += __shfl_xor(r2, 16); r2 += __shfl_xor(r2, 32);
    r3 += __shfl_xor(r3, 16); r3 += __shfl_xor(r3, 32);
    if (lane < 16) {
        *reinterpret_cast<float4*>(hagg + (size_t)id * 64 + lane * 4) =
            make_float4(r0, r1, r2, r3);
    }
}

// ===== CSR build =====
__global__ void hist_kernel(const int* __restrict__ dst, int* __restrict__ deg, int E) {
    for (int e = blockIdx.x * 256 + threadIdx.x; e < E; e += gridDim.x * 256)
        atomicAdd(&deg[dst[e]], 1);
}

__global__ __launch_bounds__(1024) void scan1(const int* __restrict__ deg,
                                              int* __restrict__ offs,
                                              int* __restrict__ part, int N) {
    const int i = blockIdx.x * 1024 + threadIdx.x;
    const int lane = threadIdx.x & 63, wid = threadIdx.x >> 6;
    const int v = (i < N) ? deg[i] : 0;
    int s = v;
    #pragma unroll
    for (int o = 1; o < 64; o <<= 1) { int t = __shfl_up(s, o); if (lane >= o) s += t; }
    __shared__ int wt[16];
    if (lane == 63) wt[wid] = s;
    __syncthreads();
    if (threadIdx.x < 16) {
        int t = wt[threadIdx.x];
        #pragma unroll
        for (int o = 1; o < 16; o <<= 1) { int u = __shfl_up(t, o); if (threadIdx.x >= o) t += u; }
        wt[threadIdx.x] = t;
    }
    __syncthreads();
    const int incl = s + (wid > 0 ? wt[wid - 1] : 0);
    if (i < N) offs[i] = incl - v;
    if (threadIdx.x == 1023) part[blockIdx.x] = incl;
}

__global__ void scan2(int* __restrict__ part, int nb) {
    if (nb <= 64) {
        const int lane = threadIdx.x;
        int v = (lane < nb) ? part[lane] : 0;
        int s = v;
        #pragma unroll
        for (int o = 1; o < 64; o <<= 1) { int t = __shfl_up(s, o); if (lane >= o) s += t; }
        if (lane < nb) part[lane] = s - v;
    } else if (threadIdx.x == 0) {
        int run = 0;
        for (int b = 0; b < nb; ++b) { int t = part[b]; part[b] = run; run += t; }
    }
}

__global__ __launch_bounds__(1024) void scan3(int* __restrict__ offs,
                                              const int* __restrict__ part, int N, int E) {
    const int i = blockIdx.x * 1024 + threadIdx.x;
    if (i < N) offs[i] += part[blockIdx.x];
    if (i == 0) offs[N] = E;
}

__global__ void scatter_kernel(const int* __restrict__ src, const int* __restrict__ dst,
                               int* __restrict__ cursor, int* __restrict__ csr_src, int E) {
    for (int e = blockIdx.x * 256 + threadIdx.x; e < E; e += gridDim.x * 256) {
        const int p = atomicAdd(&cursor[dst[e]], 1);
        csr_src[p] = src[e];
    }
}

// ===== batchnorm stats =====
__global__ void bn_stats(const float* __restrict__ hagg, float* __restrict__ sums,
                         float* __restrict__ sumsq, int N) {
    __shared__ float ls[4][64], ls2[4][64];
    const int c = threadIdx.x & 63, r = threadIdx.x >> 6;
    float s = 0.f, s2 = 0.f;
    for (int n = blockIdx.x * 4 + r; n < N; n += gridDim.x * 4) {
        const float v = hagg[(size_t)n * 64 + c];
        s += v; s2 += v * v;
    }
    ls[r][c] = s; ls2[r][c] = s2;
    __syncthreads();
    if (threadIdx.x < 64) {
        atomicAdd(&sums[c], ls[0][c] + ls[1][c] + ls[2][c] + ls[3][c]);
        atomicAdd(&sumsq[c], ls2[0][c] + ls2[1][c] + ls2[2][c] + ls2[3][c]);
    }
}

// ===== bn + relu + column sum (layer 2 epilogue) =====
__global__ void bn_reduce_z(const float* __restrict__ hagg, const float* __restrict__ sums,
                            const float* __restrict__ sumsq,
                            const float* __restrict__ g, const float* __restrict__ be,
                            float* __restrict__ zbar, int N) {
    __shared__ float ls[4][64];
    const int c = threadIdx.x & 63, r = threadIdx.x >> 6;
    const float invN = 1.0f / (float)N;
    const float mu = sums[c] * invN;
    const float var = sumsq[c] * invN - mu * mu;
    const float rs = rsqrtf(var + BN_EPS);
    const float gg = g[c], bb = be[c];
    float s = 0.f;
    for (int n = blockIdx.x * 4 + r; n < N; n += gridDim.x * 4) {
        s += fmaxf(0.f, (hagg[(size_t)n * 64 + c] - mu) * rs * gg + bb);
    }
    ls[r][c] = s;
    __syncthreads();
    if (threadIdx.x < 64) atomicAdd(&zbar[c], ls[0][c] + ls[1][c] + ls[2][c] + ls[3][c]);
}

// ===== out[j] = (zbar/N) @ Wlin + blin =====
__global__ void final_kernel(const float* __restrict__ zbar, const float* __restrict__ Wlin,
                             const float* __restrict__ blin, float* __restrict__ out, int N) {
    const int j = threadIdx.x;  // 128
    float acc = blin[j];
    const float invN = 1.0f / (float)N;
    for (int c = 0; c < 64; ++c) acc += (zbar[c] * invN) * Wlin[(size_t)c * 128 + j];
    out[j] = acc;
}

static inline char* align16(char* p) {
    return (char*)(((uintptr_t)p + 15) & ~(uintptr_t)15);
}

extern "C" void kernel_launch(void* const* d_in, const int* in_sizes, int n_in,
                              void* d_out, int out_size, void* d_ws, size_t ws_size,
                              hipStream_t stream) {
    const float* x    = (const float*)d_in[0];
    const int*   ei   = (const int*)d_in[1];
    const float* l    = (const float*)d_in[2];
    const float* Wl1  = (const float*)d_in[3];
    const float* Wr1  = (const float*)d_in[4];
    const float* att1 = (const float*)d_in[5];
    const float* g1   = (const float*)d_in[7];
    const float* be1  = (const float*)d_in[8];
    const float* Wl2  = (const float*)d_in[9];
    const float* Wr2  = (const float*)d_in[10];
    const float* att2 = (const float*)d_in[11];
    const float* g2   = (const float*)d_in[13];
    const float* be2  = (const float*)d_in[14];
    const float* Wlin = (const float*)d_in[15];
    const float* blin = (const float*)d_in[16];
    float* out = (float*)d_out;

    const int N = in_sizes[2];       // 50000
    const int E = in_sizes[1] / 2;   // 400000
    const int* src = ei;
    const int* dst = ei + E;

    // workspace carve (~66 MB)
    char* p = (char*)d_ws;
    u16* xl = (u16*)p;          p += (size_t)N * 256 * sizeof(u16);
    u16* xr = (u16*)p;          p += (size_t)N * 256 * sizeof(u16);
    float* hagg = (float*)p;    p += (size_t)N * 64 * sizeof(float);
    u16* WbfA = (u16*)p;        p += (size_t)1 * 2048 * 8 * sizeof(u16);   // 32 KB
    u16* WbfB = (u16*)p;        p += (size_t)3 * 2048 * 8 * sizeof(u16);   // 96 KB
    int* csr_src = (int*)p;     p += (size_t)E * sizeof(int);
    int* deg = (int*)p;         p += (size_t)N * sizeof(int);
    int* offs = (int*)p;        p += (size_t)(N + 1) * sizeof(int);
    int* cursor = (int*)p;      p += (size_t)N * sizeof(int);
    int* part = (int*)p;        p += 256 * sizeof(int);  p = align16(p);
    float* sums = (float*)p;    p += 64 * sizeof(float);
    float* sumsq = (float*)p;   p += 64 * sizeof(float);
    float* zbar = (float*)p;    p += 64 * sizeof(float);

    const int gemmBlocks = (N + 31) / 32;
    const int nodeBlocks = (N + 3) / 4;
    const int scanBlocks = (N + 1023) / 1024;
    const int bnBlocks = 256;

    // ===== CSR build (dst-sorted incoming edges) =====
    hipMemsetAsync(deg, 0, (size_t)N * sizeof(int), stream);
    hist_kernel<<<2048, 256, 0, stream>>>(dst, deg, E);
    scan1<<<scanBlocks, 1024, 0, stream>>>(deg, offs, part, N);
    scan2<<<1, 64, 0, stream>>>(part, scanBlocks);
    scan3<<<scanBlocks, 1024, 0, stream>>>(offs, part, N, E);
    hipMemcpyAsync(cursor, offs, (size_t)N * sizeof(int), hipMemcpyDeviceToDevice, stream);
    scatter_kernel<<<2048, 256, 0, stream>>>(src, dst, cursor, csr_src, E);

    hipMemsetAsync(sums, 0, 3 * 64 * sizeof(float), stream);   // sums+sumsq+zbar

    // ===== W prep (swizzled bf16 fragments) =====
    prep_w<<<(2048 + 255) / 256, 256, 0, stream>>>(Wl1, Wr1, WbfA, 32, 2048);
    prep_w<<<(6144 + 255) / 256, 256, 0, stream>>>(Wl2, Wr2, WbfB, 65, 6144);

    // ===== Layer 1 =====
    gemm_mfma<1, 0><<<gemmBlocks, 256, 0, stream>>>(x, nullptr, nullptr, nullptr,
                                                    nullptr, nullptr, nullptr,
                                                    WbfA, xl, xr, N);
    gat_fused<<<nodeBlocks, 256, 0, stream>>>(xl, xr, csr_src, offs, att1, hagg, N);
    bn_stats<<<bnBlocks, 256, 0, stream>>>(hagg, sums, sumsq, N);

    // ===== Layer 2 (bn+relu+concat fused into A-staging) =====
    gemm_mfma<3, 1><<<gemmBlocks, 256, 0, stream>>>(nullptr, hagg, sums, sumsq,
                                                    g1, be1, l,
                                                    WbfB, xl, xr, N);
    hipMemsetAsync(sums, 0, 2 * 64 * sizeof(float), stream);
    gat_fused<<<nodeBlocks, 256, 0, stream>>>(xl, xr, csr_src, offs, att2, hagg, N);
    bn_stats<<<bnBlocks, 256, 0, stream>>>(hagg, sums, sumsq, N);
    bn_reduce_z<<<bnBlocks, 256, 0, stream>>>(hagg, sums, sumsq, g2, be2, zbar, N);

    final_kernel<<<1, 128, 0, stream>>>(zbar, Wlin, blin, out, N);
}

// Round 6
// 252.983 us; speedup vs baseline: 3.5824x; 1.1864x over previous
//
#include <hip/hip_runtime.h>
#include <hip/hip_bf16.h>

typedef __hip_bfloat16 bf16;
typedef unsigned short u16;

#define NEG 0.2f
#define BN_EPS 1e-5f

typedef __attribute__((ext_vector_type(8))) short bfrag;   // 8 bf16 = 4 VGPRs
typedef __attribute__((ext_vector_type(4))) float ffrag;   // 4 f32 acc

__device__ __forceinline__ float u2f(u16 u) { return __uint_as_float(((unsigned)u) << 16); }
__device__ __forceinline__ float lo2f(unsigned u) { return __uint_as_float(u << 16); }
__device__ __forceinline__ float hi2f(unsigned u) { return __uint_as_float(u & 0xffff0000u); }
__device__ __forceinline__ u16 f2b(float f) { bf16 t = __float2bfloat16(f); return *(u16*)&t; }
__device__ __forceinline__ float leaky(float x) { return fmaxf(x, NEG * x); }

// ===== W prep: swizzle (Wl|Wr) f32 [K][256]x2 into per-lane MFMA B-fragment order =====
__global__ void prep_w(const float* __restrict__ Wl, const float* __restrict__ Wr,
                       u16* __restrict__ Wbf, int K, int total) {
    const int idx = blockIdx.x * 256 + threadIdx.x;
    if (idx >= total) return;
    const int l = idx & 63, n = (idx >> 6) & 31, s = idx >> 11;
    const int col = n * 16 + (l & 15);
    const int kbase = s * 32 + ((l >> 4) << 3);
    const float* __restrict__ W = (col < 256) ? (Wl + col) : (Wr + col - 256);
    u16 v[8];
    #pragma unroll
    for (int j = 0; j < 8; ++j) {
        const int k = kbase + j;
        v[j] = (k < K) ? f2b(W[(size_t)k * 256]) : (u16)0;
    }
    ushort4* d = reinterpret_cast<ushort4*>(Wbf + (size_t)idx * 8);
    d[0] = make_ushort4(v[0], v[1], v[2], v[3]);
    d[1] = make_ushort4(v[4], v[5], v[6], v[7]);
}

// ===== MFMA GEMM: xl|xr = A @ (Wl|Wr).  A = X (STAGE 0) or [relu(bn(hagg))|l|0pad] (STAGE 1) =====
template <int KSTEPS, int STAGE>
__global__ __launch_bounds__(256) void gemm_mfma(
    const float* __restrict__ Xf,
    const float* __restrict__ hagg,
    const float* __restrict__ sums, const float* __restrict__ sumsq,
    const float* __restrict__ g, const float* __restrict__ be,
    const float* __restrict__ lf,
    const u16* __restrict__ Wbf,
    u16* __restrict__ xl, u16* __restrict__ xr, int N) {

    __shared__ u16 sA[32 * 104];
    __shared__ u16 sC[32 * 512];
    __shared__ float ssc[64], ssh[64];

    const int tid = threadIdx.x;
    const int row0 = blockIdx.x * 32;

    if (STAGE == 1) {
        if (tid < 64) {
            const float invN = 1.0f / (float)N;
            const float mu = sums[tid] * invN;
            const float var = sumsq[tid] * invN - mu * mu;
            const float sc = rsqrtf(var + BN_EPS) * g[tid];
            ssc[tid] = sc;
            ssh[tid] = be[tid] - mu * sc;
        }
        __syncthreads();
        for (int idx = tid; idx < 32 * 24; idx += 256) {
            const int r = idx / 24, c4 = (idx % 24) * 4;
            const int rr = row0 + r;
            float4 v = make_float4(0.f, 0.f, 0.f, 0.f);
            if (rr < N) {
                if (c4 < 64) {
                    const float4 hv = *reinterpret_cast<const float4*>(hagg + (size_t)rr * 64 + c4);
                    v.x = fmaxf(0.f, hv.x * ssc[c4]     + ssh[c4]);
                    v.y = fmaxf(0.f, hv.y * ssc[c4 + 1] + ssh[c4 + 1]);
                    v.z = fmaxf(0.f, hv.z * ssc[c4 + 2] + ssh[c4 + 2]);
                    v.w = fmaxf(0.f, hv.w * ssc[c4 + 3] + ssh[c4 + 3]);
                } else if (c4 == 64) {
                    v.x = lf[rr];
                }
            }
            *reinterpret_cast<ushort4*>(&sA[r * 104 + c4]) =
                make_ushort4(f2b(v.x), f2b(v.y), f2b(v.z), f2b(v.w));
        }
    } else {
        for (int idx = tid; idx < 32 * 8; idx += 256) {
            const int r = idx >> 3, c4 = (idx & 7) * 4;
            const int rr = row0 + r;
            float4 v = make_float4(0.f, 0.f, 0.f, 0.f);
            if (rr < N) v = *reinterpret_cast<const float4*>(Xf + (size_t)rr * 32 + c4);
            *reinterpret_cast<ushort4*>(&sA[r * 104 + c4]) =
                make_ushort4(f2b(v.x), f2b(v.y), f2b(v.z), f2b(v.w));
        }
    }
    __syncthreads();

    const int w = tid >> 6, l = tid & 63;
    ffrag acc[2][8];
    #pragma unroll
    for (int m = 0; m < 2; ++m)
        #pragma unroll
        for (int n = 0; n < 8; ++n) acc[m][n] = ffrag{0.f, 0.f, 0.f, 0.f};

    #pragma unroll
    for (int s = 0; s < KSTEPS; ++s) {
        bfrag bf[8];
        #pragma unroll
        for (int n = 0; n < 8; ++n) {
            const int ntile = w * 8 + n;
            bf[n] = *reinterpret_cast<const bfrag*>(Wbf + ((size_t)(s * 32 + ntile) * 64 + l) * 8);
        }
        bfrag af[2];
        #pragma unroll
        for (int m = 0; m < 2; ++m) {
            const int off = (m * 16 + (l & 15)) * 104 + s * 32 + ((l >> 4) << 3);
            af[m] = *reinterpret_cast<const bfrag*>(&sA[off]);
        }
        #pragma unroll
        for (int n = 0; n < 8; ++n) {
            acc[0][n] = __builtin_amdgcn_mfma_f32_16x16x32_bf16(af[0], bf[n], acc[0][n], 0, 0, 0);
            acc[1][n] = __builtin_amdgcn_mfma_f32_16x16x32_bf16(af[1], bf[n], acc[1][n], 0, 0, 0);
        }
    }

    #pragma unroll
    for (int m = 0; m < 2; ++m)
        #pragma unroll
        for (int n = 0; n < 8; ++n) {
            const int col = w * 128 + n * 16 + (l & 15);
            const int rbase = m * 16 + ((l >> 4) << 2);
            #pragma unroll
            for (int j = 0; j < 4; ++j)
                sC[(rbase + j) * 512 + col] = f2b(acc[m][n][j]);
        }
    __syncthreads();

    for (int idx = tid; idx < 32 * 64; idx += 256) {
        const int r = idx >> 6, c8 = (idx & 63) * 8;
        const int rr = row0 + r;
        if (rr >= N) continue;
        const uint4 v = *reinterpret_cast<const uint4*>(&sC[r * 512 + c8]);
        if (c8 < 256)
            *reinterpret_cast<uint4*>(xl + (size_t)rr * 256 + c8) = v;
        else
            *reinterpret_cast<uint4*>(xr + (size_t)rr * 256 + (c8 - 256)) = v;
    }
}

// ===== fused GAT: one wave per node; 32 lanes/edge; 2 edges/iter; pipelined =====
__global__ void gat_fused(const u16* __restrict__ xl, const u16* __restrict__ xr,
                          const int* __restrict__ csr_src, const int* __restrict__ offs,
                          const float* __restrict__ att,
                          float* __restrict__ hagg, int N) {
    const int wv = threadIdx.x >> 6, lane = threadIdx.x & 63;
    const int id = blockIdx.x * 4 + wv;
    if (id >= N) return;
    const int half = lane >> 5;        // which edge of the pair
    const int hl = lane & 31;          // lane within edge: holds cols hl*8 .. hl*8+7

    // att + xr for this lane's 8 columns
    const float4 av0 = *reinterpret_cast<const float4*>(att + hl * 8);
    const float4 av1 = *reinterpret_cast<const float4*>(att + hl * 8 + 4);
    const uint4 bu = *reinterpret_cast<const uint4*>(xr + (size_t)id * 256 + hl * 8);
    const float b0 = lo2f(bu.x), b1 = hi2f(bu.x), b2 = lo2f(bu.y), b3 = hi2f(bu.y);
    const float b4 = lo2f(bu.z), b5 = hi2f(bu.z), b6 = lo2f(bu.w), b7 = hi2f(bu.w);

    const int e0 = offs[id];
    const int L = offs[id + 1] - e0;   // real incoming edges; virtual list = self + L

    // prologue: virtual idx i = -1 (self) for half 0, 0 for half 1
    const int i0 = -1 + half;
    int s_cur = (i0 < L && i0 >= 0) ? csr_src[e0 + i0] : id;
    uint4 a_cur = *reinterpret_cast<const uint4*>(xl + (size_t)s_cur * 256 + hl * 8);

    float ax0 = 0.f, ax1 = 0.f, ax2 = 0.f, ax3 = 0.f;
    float ax4 = 0.f, ax5 = 0.f, ax6 = 0.f, ax7 = 0.f;
    float denom = 0.f;

    for (int ib = -1; ib < L; ib += 2) {
        // prefetch next pair (wave-uniform condition)
        uint4 a_nxt;
        const bool more = (ib + 2) < L;
        if (more) {
            const int inx = ib + 2 + half;
            const int eidx = e0 + ((inx < L) ? inx : (L - 1));
            const int snx = (inx < L) ? csr_src[eidx] : id;
            a_nxt = *reinterpret_cast<const uint4*>(xl + (size_t)snx * 256 + hl * 8);
        }

        // process current pair
        const float x0 = lo2f(a_cur.x), x1 = hi2f(a_cur.x);
        const float x2 = lo2f(a_cur.y), x3 = hi2f(a_cur.y);
        const float x4 = lo2f(a_cur.z), x5 = hi2f(a_cur.z);
        const float x6 = lo2f(a_cur.w), x7 = hi2f(a_cur.w);

        float p = av0.x * leaky(x0 + b0) + av0.y * leaky(x1 + b1)
                + av0.z * leaky(x2 + b2) + av0.w * leaky(x3 + b3)
                + av1.x * leaky(x4 + b4) + av1.y * leaky(x5 + b5)
                + av1.z * leaky(x6 + b6) + av1.w * leaky(x7 + b7);
        p += __shfl_xor(p, 1);
        p += __shfl_xor(p, 2);
        p += __shfl_xor(p, 4);     // 8-lane head-group reduce

        const bool valid = (ib + half) < L;   // i in [-1, L)
        const float ev = valid ? __expf(p) : 0.f;
        denom += ev;
        ax0 += ev * x0; ax1 += ev * x1; ax2 += ev * x2; ax3 += ev * x3;
        ax4 += ev * x4; ax5 += ev * x5; ax6 += ev * x6; ax7 += ev * x7;

        a_cur = a_nxt;
    }

    // total denominator: sum the two halves (uniform within 8-lane head group)
    denom += __shfl_xor(denom, 32);
    const float s = 0.25f / denom;
    float r0 = ax0 * s, r1 = ax1 * s, r2 = ax2 * s, r3 = ax3 * s;
    float r4 = ax4 * s, r5 = ax5 * s, r6 = ax6 * s, r7 = ax7 * s;

    // sum across 4 head groups (xor 8, 16) and across halves (xor 32)
    #define RED(r) r += __shfl_xor(r, 8); r += __shfl_xor(r, 16); r += __shfl_xor(r, 32);
    RED(r0) RED(r1) RED(r2) RED(r3) RED(r4) RED(r5) RED(r6) RED(r7)
    #undef RED

    if (lane < 8) {   // half 0, hl<8: dims hl*8 .. hl*8+7
        float* o = hagg + (size_t)id * 64 + lane * 8;
        *reinterpret_cast<float4*>(o)     = make_float4(r0, r1, r2, r3);
        *reinterpret_cast<float4*>(o + 4) = make_float4(r4, r5, r6, r7);
    }
}

// ===== CSR build =====
__global__ void hist_kernel(const int* __restrict__ dst, int* __restrict__ deg, int E) {
    for (int e = blockIdx.x * 256 + threadIdx.x; e < E; e += gridDim.x * 256)
        atomicAdd(&deg[dst[e]], 1);
}

__global__ __launch_bounds__(1024) void scan1(const int* __restrict__ deg,
                                              int* __restrict__ offs,
                                              int* __restrict__ part, int N) {
    const int i = blockIdx.x * 1024 + threadIdx.x;
    const int lane = threadIdx.x & 63, wid = threadIdx.x >> 6;
    const int v = (i < N) ? deg[i] : 0;
    int s = v;
    #pragma unroll
    for (int o = 1; o < 64; o <<= 1) { int t = __shfl_up(s, o); if (lane >= o) s += t; }
    __shared__ int wt[16];
    if (lane == 63) wt[wid] = s;
    __syncthreads();
    if (threadIdx.x < 16) {
        int t = wt[threadIdx.x];
        #pragma unroll
        for (int o = 1; o < 16; o <<= 1) { int u = __shfl_up(t, o); if (threadIdx.x >= o) t += u; }
        wt[threadIdx.x] = t;
    }
    __syncthreads();
    const int incl = s + (wid > 0 ? wt[wid - 1] : 0);
    if (i < N) offs[i] = incl - v;
    if (threadIdx.x == 1023) part[blockIdx.x] = incl;
}

__global__ void scan2(int* __restrict__ part, int nb) {
    if (nb <= 64) {
        const int lane = threadIdx.x;
        int v = (lane < nb) ? part[lane] : 0;
        int s = v;
        #pragma unroll
        for (int o = 1; o < 64; o <<= 1) { int t = __shfl_up(s, o); if (lane >= o) s += t; }
        if (lane < nb) part[lane] = s - v;
    } else if (threadIdx.x == 0) {
        int run = 0;
        for (int b = 0; b < nb; ++b) { int t = part[b]; part[b] = run; run += t; }
    }
}

__global__ __launch_bounds__(1024) void scan3(int* __restrict__ offs, int* __restrict__ cursor,
                                              const int* __restrict__ part, int N, int E) {
    const int i = blockIdx.x * 1024 + threadIdx.x;
    if (i < N) {
        const int v = offs[i] + part[blockIdx.x];
        offs[i] = v;
        cursor[i] = v;
    }
    if (i == 0) offs[N] = E;
}

__global__ void scatter_kernel(const int* __restrict__ src, const int* __restrict__ dst,
                               int* __restrict__ cursor, int* __restrict__ csr_src, int E) {
    for (int e = blockIdx.x * 256 + threadIdx.x; e < E; e += gridDim.x * 256) {
        const int p = atomicAdd(&cursor[dst[e]], 1);
        csr_src[p] = src[e];
    }
}

// ===== batchnorm stats =====
__global__ void bn_stats(const float* __restrict__ hagg, float* __restrict__ sums,
                         float* __restrict__ sumsq, int N) {
    __shared__ float ls[4][64], ls2[4][64];
    const int c = threadIdx.x & 63, r = threadIdx.x >> 6;
    float s = 0.f, s2 = 0.f;
    for (int n = blockIdx.x * 4 + r; n < N; n += gridDim.x * 4) {
        const float v = hagg[(size_t)n * 64 + c];
        s += v; s2 += v * v;
    }
    ls[r][c] = s; ls2[r][c] = s2;
    __syncthreads();
    if (threadIdx.x < 64) {
        atomicAdd(&sums[c], ls[0][c] + ls[1][c] + ls[2][c] + ls[3][c]);
        atomicAdd(&sumsq[c], ls2[0][c] + ls2[1][c] + ls2[2][c] + ls2[3][c]);
    }
}

// ===== bn + relu + column sum (layer 2 epilogue) =====
__global__ void bn_reduce_z(const float* __restrict__ hagg, const float* __restrict__ sums,
                            const float* __restrict__ sumsq,
                            const float* __restrict__ g, const float* __restrict__ be,
                            float* __restrict__ zbar, int N) {
    __shared__ float ls[4][64];
    const int c = threadIdx.x & 63, r = threadIdx.x >> 6;
    const float invN = 1.0f / (float)N;
    const float mu = sums[c] * invN;
    const float var = sumsq[c] * invN - mu * mu;
    const float rs = rsqrtf(var + BN_EPS);
    const float gg = g[c], bb = be[c];
    float s = 0.f;
    for (int n = blockIdx.x * 4 + r; n < N; n += gridDim.x * 4) {
        s += fmaxf(0.f, (hagg[(size_t)n * 64 + c] - mu) * rs * gg + bb);
    }
    ls[r][c] = s;
    __syncthreads();
    if (threadIdx.x < 64) atomicAdd(&zbar[c], ls[0][c] + ls[1][c] + ls[2][c] + ls[3][c]);
}

// ===== out[j] = (zbar/N) @ Wlin + blin =====
__global__ void final_kernel(const float* __restrict__ zbar, const float* __restrict__ Wlin,
                             const float* __restrict__ blin, float* __restrict__ out, int N) {
    const int j = threadIdx.x;  // 128
    float acc = blin[j];
    const float invN = 1.0f / (float)N;
    for (int c = 0; c < 64; ++c) acc += (zbar[c] * invN) * Wlin[(size_t)c * 128 + j];
    out[j] = acc;
}

static inline char* align16(char* p) {
    return (char*)(((uintptr_t)p + 15) & ~(uintptr_t)15);
}

extern "C" void kernel_launch(void* const* d_in, const int* in_sizes, int n_in,
                              void* d_out, int out_size, void* d_ws, size_t ws_size,
                              hipStream_t stream) {
    const float* x    = (const float*)d_in[0];
    const int*   ei   = (const int*)d_in[1];
    const float* l    = (const float*)d_in[2];
    const float* Wl1  = (const float*)d_in[3];
    const float* Wr1  = (const float*)d_in[4];
    const float* att1 = (const float*)d_in[5];
    const float* g1   = (const float*)d_in[7];
    const float* be1  = (const float*)d_in[8];
    const float* Wl2  = (const float*)d_in[9];
    const float* Wr2  = (const float*)d_in[10];
    const float* att2 = (const float*)d_in[11];
    const float* g2   = (const float*)d_in[13];
    const float* be2  = (const float*)d_in[14];
    const float* Wlin = (const float*)d_in[15];
    const float* blin = (const float*)d_in[16];
    float* out = (float*)d_out;

    const int N = in_sizes[2];       // 50000
    const int E = in_sizes[1] / 2;   // 400000
    const int* src = ei;
    const int* dst = ei + E;

    // workspace carve (~66 MB)
    char* p = (char*)d_ws;
    u16* xl = (u16*)p;          p += (size_t)N * 256 * sizeof(u16);
    u16* xr = (u16*)p;          p += (size_t)N * 256 * sizeof(u16);
    float* hagg = (float*)p;    p += (size_t)N * 64 * sizeof(float);
    u16* WbfA = (u16*)p;        p += (size_t)1 * 2048 * 8 * sizeof(u16);
    u16* WbfB = (u16*)p;        p += (size_t)3 * 2048 * 8 * sizeof(u16);
    int* csr_src = (int*)p;     p += (size_t)E * sizeof(int);
    int* deg = (int*)p;         p += (size_t)N * sizeof(int);
    int* offs = (int*)p;        p += (size_t)(N + 1) * sizeof(int);
    int* cursor = (int*)p;      p += (size_t)N * sizeof(int);
    int* part = (int*)p;        p += 256 * sizeof(int);  p = align16(p);
    float* sums = (float*)p;    p += 64 * sizeof(float);
    float* sumsq = (float*)p;   p += 64 * sizeof(float);
    float* zbar = (float*)p;    p += 64 * sizeof(float);

    const int gemmBlocks = (N + 31) / 32;
    const int nodeBlocks = (N + 3) / 4;
    const int scanBlocks = (N + 1023) / 1024;
    const int bnBlocks = 256;

    // ===== CSR build (dst-sorted incoming edges) =====
    hipMemsetAsync(deg, 0, (size_t)N * sizeof(int), stream);
    hist_kernel<<<2048, 256, 0, stream>>>(dst, deg, E);
    scan1<<<scanBlocks, 1024, 0, stream>>>(deg, offs, part, N);
    scan2<<<1, 64, 0, stream>>>(part, scanBlocks);
    scan3<<<scanBlocks, 1024, 0, stream>>>(offs, cursor, part, N, E);
    scatter_kernel<<<2048, 256, 0, stream>>>(src, dst, cursor, csr_src, E);

    hipMemsetAsync(sums, 0, 3 * 64 * sizeof(float), stream);   // sums+sumsq+zbar

    // ===== W prep (swizzled bf16 fragments) =====
    prep_w<<<(2048 + 255) / 256, 256, 0, stream>>>(Wl1, Wr1, WbfA, 32, 2048);
    prep_w<<<(6144 + 255) / 256, 256, 0, stream>>>(Wl2, Wr2, WbfB, 65, 6144);

    // ===== Layer 1 =====
    gemm_mfma<1, 0><<<gemmBlocks, 256, 0, stream>>>(x, nullptr, nullptr, nullptr,
                                                    nullptr, nullptr, nullptr,
                                                    WbfA, xl, xr, N);
    gat_fused<<<nodeBlocks, 256, 0, stream>>>(xl, xr, csr_src, offs, att1, hagg, N);
    bn_stats<<<bnBlocks, 256, 0, stream>>>(hagg, sums, sumsq, N);

    // ===== Layer 2 (bn+relu+concat fused into A-staging) =====
    gemm_mfma<3, 1><<<gemmBlocks, 256, 0, stream>>>(nullptr, hagg, sums, sumsq,
                                                    g1, be1, l,
                                                    WbfB, xl, xr, N);
    hipMemsetAsync(sums, 0, 2 * 64 * sizeof(float), stream);
    gat_fused<<<nodeBlocks, 256, 0, stream>>>(xl, xr, csr_src, offs, att2, hagg, N);
    bn_stats<<<bnBlocks, 256, 0, stream>>>(hagg, sums, sumsq, N);
    bn_reduce_z<<<bnBlocks, 256, 0, stream>>>(hagg, sums, sumsq, g2, be2, zbar, N);

    final_kernel<<<1, 128, 0, stream>>>(zbar, Wlin, blin, out, N);
}